// Round 8
// baseline (1082.723 us; speedup 1.0000x reference)
//
#include <hip/hip_runtime.h>
#include <hip/hip_bf16.h>
#include <hip/hip_cooperative_groups.h>

namespace cg = cooperative_groups;

typedef __attribute__((ext_vector_type(8))) short bf16x8;
typedef __attribute__((ext_vector_type(4))) float f32x4;

static __device__ __forceinline__ float bflo(unsigned int w) {
    union { unsigned int i; float f; } u; u.i = w << 16; return u.f;
}
static __device__ __forceinline__ float bfhi(unsigned int w) {
    union { unsigned int i; float f; } u; u.i = w & 0xffff0000u; return u.f;
}
static __device__ __forceinline__ unsigned short f2bf(float f) {
    __hip_bfloat16 h = __float2bfloat16(f);
    union { __hip_bfloat16 b; unsigned short s; } u; u.b = h; return u.s;
}

// ---------------------------------------------------------------------------
// per-node aggregation, one wave: out[v] = dinv[v]*(sum dinv[s]*in[s] + dinv[v]*in[v]) (+bias, relu)
// ---------------------------------------------------------------------------
static __device__ __forceinline__ void agg_node(
    const unsigned short* __restrict__ in, unsigned short* __restrict__ out,
    int v, int lane, const int* __restrict__ row_ptr, const int* __restrict__ cnt,
    const int2* __restrict__ edges, const float* __restrict__ dinv,
    const float* __restrict__ bias, int relu) {
    int l16 = lane & 15;
    int g = lane >> 4;
    float acc[8] = {0.f, 0.f, 0.f, 0.f, 0.f, 0.f, 0.f, 0.f};
    int s0 = row_ptr[v];
    int s1 = s0 + cnt[v];
    int e = s0 + g;
    for (; e + 4 < s1; e += 8) {
        int2 pa = edges[e];
        int2 pb = edges[e + 4];
        float wa = __int_as_float(pa.y);
        float wb = __int_as_float(pb.y);
        uint4 ra = *reinterpret_cast<const uint4*>(in + (size_t)pa.x * 128 + l16 * 8);
        uint4 rb = *reinterpret_cast<const uint4*>(in + (size_t)pb.x * 128 + l16 * 8);
        acc[0] = fmaf(wa, bflo(ra.x), acc[0]);
        acc[1] = fmaf(wa, bfhi(ra.x), acc[1]);
        acc[2] = fmaf(wa, bflo(ra.y), acc[2]);
        acc[3] = fmaf(wa, bfhi(ra.y), acc[3]);
        acc[4] = fmaf(wa, bflo(ra.z), acc[4]);
        acc[5] = fmaf(wa, bfhi(ra.z), acc[5]);
        acc[6] = fmaf(wa, bflo(ra.w), acc[6]);
        acc[7] = fmaf(wa, bfhi(ra.w), acc[7]);
        acc[0] = fmaf(wb, bflo(rb.x), acc[0]);
        acc[1] = fmaf(wb, bfhi(rb.x), acc[1]);
        acc[2] = fmaf(wb, bflo(rb.y), acc[2]);
        acc[3] = fmaf(wb, bfhi(rb.y), acc[3]);
        acc[4] = fmaf(wb, bflo(rb.z), acc[4]);
        acc[5] = fmaf(wb, bfhi(rb.z), acc[5]);
        acc[6] = fmaf(wb, bflo(rb.w), acc[6]);
        acc[7] = fmaf(wb, bfhi(rb.w), acc[7]);
    }
    if (e < s1) {
        int2 pa = edges[e];
        float wa = __int_as_float(pa.y);
        uint4 ra = *reinterpret_cast<const uint4*>(in + (size_t)pa.x * 128 + l16 * 8);
        acc[0] = fmaf(wa, bflo(ra.x), acc[0]);
        acc[1] = fmaf(wa, bfhi(ra.x), acc[1]);
        acc[2] = fmaf(wa, bflo(ra.y), acc[2]);
        acc[3] = fmaf(wa, bfhi(ra.y), acc[3]);
        acc[4] = fmaf(wa, bflo(ra.z), acc[4]);
        acc[5] = fmaf(wa, bfhi(ra.z), acc[5]);
        acc[6] = fmaf(wa, bflo(ra.w), acc[6]);
        acc[7] = fmaf(wa, bfhi(ra.w), acc[7]);
    }
#pragma unroll
    for (int d = 0; d < 8; ++d) {
        acc[d] += __shfl_xor(acc[d], 16, 64);
        acc[d] += __shfl_xor(acc[d], 32, 64);
    }
    if (g == 0) {
        float dv = dinv[v];
        uint4 sp = *reinterpret_cast<const uint4*>(in + (size_t)v * 128 + l16 * 8);
        float self[8] = {bflo(sp.x), bfhi(sp.x), bflo(sp.y), bfhi(sp.y),
                         bflo(sp.z), bfhi(sp.z), bflo(sp.w), bfhi(sp.w)};
        union { unsigned short s[8]; uint4 u; } o;
#pragma unroll
        for (int d = 0; d < 8; ++d) {
            float val = (acc[d] + dv * self[d]) * dv;
            if (bias) val += bias[l16 * 8 + d];
            if (relu) val = fmaxf(val, 0.f);
            o.s[d] = f2bf(val);
        }
        *reinterpret_cast<uint4*>(out + (size_t)v * 128 + l16 * 8) = o.u;
    }
}

// ---------------------------------------------------------------------------
// one wave computes a 16xN_TILE(=64) tile of C = act(A @ Bt^T + bias)
// ---------------------------------------------------------------------------
static __device__ __forceinline__ void gemm_tile(
    const unsigned short* __restrict__ A, const unsigned short* __restrict__ Bt,
    const float* __restrict__ bias, unsigned short* __restrict__ C,
    int r0, int bn, int N, int K, int relu, int lane) {
    int lr = lane & 15, kg = (lane >> 4) * 8;
    f32x4 acc[4] = {{0,0,0,0},{0,0,0,0},{0,0,0,0},{0,0,0,0}};
    for (int k0 = 0; k0 < K; k0 += 32) {
        bf16x8 a = *reinterpret_cast<const bf16x8*>(A + (size_t)(r0 + lr) * K + k0 + kg);
#pragma unroll
        for (int c = 0; c < 4; ++c) {
            bf16x8 b = *reinterpret_cast<const bf16x8*>(Bt + (size_t)(bn + c * 16 + lr) * K + k0 + kg);
            acc[c] = __builtin_amdgcn_mfma_f32_16x16x32_bf16(a, b, acc[c], 0, 0, 0);
        }
    }
    int rq = (lane >> 4) * 4;
#pragma unroll
    for (int c = 0; c < 4; ++c) {
        int col = bn + c * 16 + lr;
        float bs = bias ? bias[col] : 0.f;
#pragma unroll
        for (int q = 0; q < 4; ++q) {
            float vv = acc[c][q] + bs;
            if (relu) vv = fmaxf(vv, 0.f);
            C[(size_t)(r0 + rq + q) * N + col] = f2bf(vv);
        }
    }
}

// ---------------------------------------------------------------------------
// mega kernel: all phases up to h3. phase=-1: cooperative, grid.sync between
// phases. phase>=0: run only that phase (fallback, one launch per phase).
// ---------------------------------------------------------------------------
__global__ __launch_bounds__(256, 4) void mega_kernel(
    const int* __restrict__ x, const int* __restrict__ srcp, const int* __restrict__ dstp,
    const float* __restrict__ emb,
    const float* __restrict__ W1, const float* __restrict__ b1,
    const float* __restrict__ W2, const float* __restrict__ b2,
    const float* __restrict__ Wl, const float* __restrict__ bl,
    int* __restrict__ counts, int* __restrict__ row_ptr, int* __restrict__ wp,
    float* __restrict__ dinv, int2* __restrict__ edges,
    unsigned short* __restrict__ W1t, unsigned short* __restrict__ W2t,
    unsigned short* __restrict__ Wlt,
    unsigned short* __restrict__ h0b, unsigned short* __restrict__ z1b,
    unsigned short* __restrict__ h1b, unsigned short* __restrict__ hw2b,
    unsigned short* __restrict__ h2b, unsigned short* __restrict__ h3b,
    int nu, int n, int E, int phase) {
    __shared__ int sums[256];
    const int tid = blockIdx.x * blockDim.x + threadIdx.x;
    const int nthr = gridDim.x * blockDim.x;
    const int wave = tid >> 6;
    const int nwave = nthr >> 6;
    const int lane = threadIdx.x & 63;
    const int tiles_m = n >> 4;

    // ---- P0: prep (h0 bf16, weight transposes, zero counters) ----
    if (phase < 0 || phase == 0) {
        int H = n * 16;
        int total = H + 73728 + 2 * n;
        for (int i = tid; i < total; i += nthr) {
            if (i < H) {
                int node = i >> 4, c8 = i & 15;
                int row = (node < nu) ? 0 : (x[node] - nu + 1);
                float4 f0 = reinterpret_cast<const float4*>(emb)[(size_t)row * 32 + c8 * 2];
                float4 f1 = reinterpret_cast<const float4*>(emb)[(size_t)row * 32 + c8 * 2 + 1];
                union { unsigned short s[8]; uint4 v; } o;
                o.s[0] = f2bf(f0.x); o.s[1] = f2bf(f0.y); o.s[2] = f2bf(f0.z); o.s[3] = f2bf(f0.w);
                o.s[4] = f2bf(f1.x); o.s[5] = f2bf(f1.y); o.s[6] = f2bf(f1.z); o.s[7] = f2bf(f1.w);
                *reinterpret_cast<uint4*>(h0b + (size_t)node * 128 + c8 * 8) = o.v;
                continue;
            }
            int j = i - H;
            if (j < 32768) {
                int nn = j >> 7, kk = j & 127;
                W1t[j] = f2bf(W1[kk * 256 + nn]);
                continue;
            }
            if (j < 65536) {
                int jj = j - 32768;
                int nn = jj >> 8, kk = jj & 255;
                W2t[jj] = f2bf(W2[kk * 128 + nn]);
                continue;
            }
            if (j < 73728) {
                int jj = j - 65536;
                int nn = jj >> 7, kk = jj & 127;
                Wlt[jj] = f2bf(Wl[kk * 64 + nn]);
                continue;
            }
            int z = j - 73728;
            if (z < n) { counts[z] = 0; continue; }
            z -= n;
            if (z < n) { wp[z] = 0; }
        }
    }
    if (phase < 0) cg::this_grid().sync();

    // ---- P1: degree histogram ----
    if (phase < 0 || phase == 1) {
        for (int e = tid; e < E; e += nthr) atomicAdd(&counts[dstp[e]], 1);
    }
    if (phase < 0) cg::this_grid().sync();

    // ---- P2: scan (block 0 only), column-major bucket order ----
    if (phase < 0 || phase == 2) {
        if (blockIdx.x == 0) {
            int t = threadIdx.x;
            int rows = n >> 8;
            int s = 0;
            for (int i = 0; i < rows; ++i) s += counts[i * 256 + t];
            sums[t] = s;
            __syncthreads();
#pragma unroll
            for (int off = 1; off < 256; off <<= 1) {
                int v = (t >= off) ? sums[t - off] : 0;
                __syncthreads();
                sums[t] += v;
                __syncthreads();
            }
            int run = (t > 0) ? sums[t - 1] : 0;
            for (int i = 0; i < rows; ++i) {
                int v = i * 256 + t;
                int c = counts[v];
                row_ptr[v] = run;
                dinv[v] = rsqrtf((float)(c + 1));
                run += c;
            }
        }
    }
    if (phase < 0) cg::this_grid().sync();

    // ---- P3: scatter packed {src, dinv[src]} ----
    if (phase < 0 || phase == 3) {
        for (int e = tid; e < E; e += nthr) {
            int dd = dstp[e];
            int ss = srcp[e];
            int p = atomicAdd(&wp[dd], 1);
            int2 pk;
            pk.x = ss;
            pk.y = __float_as_int(dinv[ss]);
            edges[row_ptr[dd] + p] = pk;
        }
    }
    if (phase < 0) cg::this_grid().sync();

    // ---- P4: agg1  z1 = A·h0 ----
    if (phase < 0 || phase == 4) {
        for (int v = wave; v < n; v += nwave)
            agg_node(h0b, z1b, v, lane, row_ptr, counts, edges, dinv, nullptr, 0);
    }
    if (phase < 0) cg::this_grid().sync();

    // ---- P5: gemm1  h1 = relu(z1 @ W1 + b1)  (K=128, N=256) ----
    if (phase < 0 || phase == 5) {
        int tiles = tiles_m * 4;
        for (int t = wave; t < tiles; t += nwave) {
            int r0 = (t % tiles_m) * 16;
            int bn = (t / tiles_m) * 64;
            gemm_tile(z1b, W1t, b1, h1b, r0, bn, 256, 128, 1, lane);
        }
    }
    if (phase < 0) cg::this_grid().sync();

    // ---- P6: gemm2  hw2 = h1 @ W2  (K=256, N=128) ----
    if (phase < 0 || phase == 6) {
        int tiles = tiles_m * 2;
        for (int t = wave; t < tiles; t += nwave) {
            int r0 = (t % tiles_m) * 16;
            int bn = (t / tiles_m) * 64;
            gemm_tile(h1b, W2t, nullptr, hw2b, r0, bn, 128, 256, 0, lane);
        }
    }
    if (phase < 0) cg::this_grid().sync();

    // ---- P7: agg2  h2 = relu(A·hw2 + b2) ----
    if (phase < 0 || phase == 7) {
        for (int v = wave; v < n; v += nwave)
            agg_node(hw2b, h2b, v, lane, row_ptr, counts, edges, dinv, b2, 1);
    }
    if (phase < 0) cg::this_grid().sync();

    // ---- P8: gemm3  h3 = relu(h2 @ Wl + bl)  (K=128, N=64) ----
    if (phase < 0 || phase == 8) {
        for (int t = wave; t < tiles_m; t += nwave) {
            int r0 = (t % tiles_m) * 16;
            gemm_tile(h2b, Wlt, bl, h3b, r0, 0, 64, 128, 1, lane);
        }
    }
}

// ---------------------------------------------------------------------------
// final: out[i][j] = clip(dot64(users[i], items[j]), 1, 5)  via bf16 MFMA.
// Block = 4 waves; each wave a 64x64 tile -> block tile 128x128.
// Epilogue: per-wave LDS transpose chunk -> float4 stores (256B segments).
// ---------------------------------------------------------------------------
__global__ __launch_bounds__(256) void final_gemm_kernel(
    const short* __restrict__ h3b, float* __restrict__ out, int nu, int ni) {
    __shared__ float tile[4][16][65];
    int wid = threadIdx.x >> 6, lane = threadIdx.x & 63;
    int row0 = blockIdx.x * 128 + (wid >> 1) * 64;
    int col0 = blockIdx.y * 128 + (wid & 1) * 64;
    int lr = lane & 15;
    int kg = (lane >> 4) * 8;
    const short* Au = h3b;
    const short* Bi = h3b + (size_t)nu * 64;
    bf16x8 a[4][2], b[4][2];
#pragma unroll
    for (int r = 0; r < 4; ++r)
#pragma unroll
        for (int kt = 0; kt < 2; ++kt) {
            a[r][kt] = *reinterpret_cast<const bf16x8*>(Au + (size_t)(row0 + r * 16 + lr) * 64 + kt * 32 + kg);
            b[r][kt] = *reinterpret_cast<const bf16x8*>(Bi + (size_t)(col0 + r * 16 + lr) * 64 + kt * 32 + kg);
        }
    f32x4 acc[4][4];
#pragma unroll
    for (int r = 0; r < 4; ++r)
#pragma unroll
        for (int c = 0; c < 4; ++c) {
            f32x4 z = {0.f, 0.f, 0.f, 0.f};
            z = __builtin_amdgcn_mfma_f32_16x16x32_bf16(a[r][0], b[c][0], z, 0, 0, 0);
            z = __builtin_amdgcn_mfma_f32_16x16x32_bf16(a[r][1], b[c][1], z, 0, 0, 0);
            acc[r][c] = z;
        }
    int rq = (lane >> 4) * 4;
    int orow = lane >> 4;
#pragma unroll
    for (int r = 0; r < 4; ++r) {
        __syncthreads();
#pragma unroll
        for (int c = 0; c < 4; ++c)
#pragma unroll
            for (int q = 0; q < 4; ++q) {
                float v = acc[r][c][q];
                v = fminf(fmaxf(v, 1.f), 5.f);
                tile[wid][rq + q][c * 16 + lr] = v;
            }
        __syncthreads();
#pragma unroll
        for (int rr = 0; rr < 4; ++rr) {
            float4 vv = *reinterpret_cast<const float4*>(&tile[wid][rr * 4 + orow][lr * 4]);
            *reinterpret_cast<float4*>(
                &out[(size_t)(row0 + r * 16 + rr * 4 + orow) * ni + col0 + lr * 4]) = vv;
        }
    }
}

// ---------------------------------------------------------------------------
extern "C" void kernel_launch(void* const* d_in, const int* in_sizes, int n_in,
                              void* d_out, int out_size, void* d_ws, size_t ws_size,
                              hipStream_t stream) {
    const int*   x   = (const int*)d_in[0];
    const int*   ei  = (const int*)d_in[1];
    const float* emb = (const float*)d_in[3];
    const float* W1  = (const float*)d_in[4];
    const float* b1  = (const float*)d_in[5];
    const float* W2  = (const float*)d_in[6];
    const float* b2  = (const float*)d_in[7];
    const float* Wl  = (const float*)d_in[8];
    const float* bl  = (const float*)d_in[9];
    float* out = (float*)d_out;

    int n   = in_sizes[0];                 // 16384
    int E   = in_sizes[1] / 2;             // 524288
    const int h1d = in_sizes[5];           // 256
    const int d   = in_sizes[4] / h1d;     // 128
    const int embrows = in_sizes[3] / d;   // 8193
    int nu  = n - (embrows - 1);           // 8192
    const int ni  = n - nu;                // 8192

    const int* srcp = ei;
    const int* dstp = ei + E;

    char* w = (char*)d_ws;
    int*   counts  = (int*)(w + 0);
    int*   row_ptr = (int*)(w + (64 << 10));
    int*   wp      = (int*)(w + (128 << 10));
    float* dinv    = (float*)(w + (192 << 10));
    unsigned short* W1t = (unsigned short*)(w + (256 << 10));
    unsigned short* W2t = (unsigned short*)(w + (320 << 10));
    unsigned short* Wlt = (unsigned short*)(w + (384 << 10));
    int2*  edges   = (int2*)(w + (1 << 20));
    unsigned short* h0b  = (unsigned short*)(w + (8  << 20));
    unsigned short* z1b  = (unsigned short*)(w + (12 << 20));
    unsigned short* h1b  = (unsigned short*)(w + (16 << 20));
    unsigned short* hw2b = (unsigned short*)(w + (24 << 20));
    unsigned short* h2b  = (unsigned short*)(w + (28 << 20));
    unsigned short* h3b  = (unsigned short*)(w + (32 << 20));

    int phase = -1;
    void* args[] = {
        (void*)&x, (void*)&srcp, (void*)&dstp, (void*)&emb,
        (void*)&W1, (void*)&b1, (void*)&W2, (void*)&b2, (void*)&Wl, (void*)&bl,
        (void*)&counts, (void*)&row_ptr, (void*)&wp, (void*)&dinv, (void*)&edges,
        (void*)&W1t, (void*)&W2t, (void*)&Wlt,
        (void*)&h0b, (void*)&z1b, (void*)&h1b, (void*)&hw2b, (void*)&h2b, (void*)&h3b,
        (void*)&nu, (void*)&n, (void*)&E, (void*)&phase
    };
    hipError_t err = hipLaunchCooperativeKernel(
        (const void*)mega_kernel, dim3(1024), dim3(256), args, 0, stream);
    if (err != hipSuccess) {
        // fallback: one launch per phase (no grid.sync executed)
        for (int p = 0; p <= 8; ++p) {
            mega_kernel<<<1024, 256, 0, stream>>>(
                x, srcp, dstp, emb, W1, b1, W2, b2, Wl, bl,
                counts, row_ptr, wp, dinv, edges, W1t, W2t, Wlt,
                h0b, z1b, h1b, hw2b, h2b, h3b, nu, n, E, p);
        }
    }

    // result = clip(users @ items.T, 1, 5)
    {
        dim3 g(nu / 128, ni / 128);
        final_gemm_kernel<<<g, 256, 0, stream>>>((const short*)h3b, out, nu, ni);
    }
}

// Round 9
// 190.655 us; speedup vs baseline: 5.6790x; 5.6790x over previous
//
#include <hip/hip_runtime.h>
#include <hip/hip_bf16.h>

typedef __attribute__((ext_vector_type(8))) short bf16x8;
typedef __attribute__((ext_vector_type(4))) float f32x4;

static __device__ __forceinline__ float bflo(unsigned int w) {
    union { unsigned int i; float f; } u; u.i = w << 16; return u.f;
}
static __device__ __forceinline__ float bfhi(unsigned int w) {
    union { unsigned int i; float f; } u; u.i = w & 0xffff0000u; return u.f;
}
static __device__ __forceinline__ unsigned short f2bf(float f) {
    __hip_bfloat16 h = __float2bfloat16(f);
    union { __hip_bfloat16 b; unsigned short s; } u; u.b = h; return u.s;
}

// ---------------------------------------------------------------------------
// degree histogram over dst
// ---------------------------------------------------------------------------
__global__ void count_kernel(const int* __restrict__ dst, int* __restrict__ counts, int E) {
    int e = blockIdx.x * blockDim.x + threadIdx.x;
    if (e < E) atomicAdd(&counts[dst[e]], 1);
}

// ---------------------------------------------------------------------------
// single-block scan, coalesced column-major bucket order.
// Consumers use row_ptr[v] + counts[v] as bucket end (order-free).
// ---------------------------------------------------------------------------
__global__ __launch_bounds__(256) void scan_kernel(const int* __restrict__ counts,
                                                   int* __restrict__ row_ptr,
                                                   float* __restrict__ dinv, int n) {
    int t = threadIdx.x;
    int rows = n >> 8;
    int s = 0;
    for (int i = 0; i < rows; ++i) s += counts[i * 256 + t];
    __shared__ int sums[256];
    sums[t] = s;
    __syncthreads();
#pragma unroll
    for (int off = 1; off < 256; off <<= 1) {
        int v = (t >= off) ? sums[t - off] : 0;
        __syncthreads();
        sums[t] += v;
        __syncthreads();
    }
    int run = (t > 0) ? sums[t - 1] : 0;
    for (int i = 0; i < rows; ++i) {
        int v = i * 256 + t;
        int c = counts[v];
        row_ptr[v] = run;
        dinv[v] = rsqrtf((float)(c + 1));
        run += c;
    }
}

// ---------------------------------------------------------------------------
// scatter edges into CSR buckets as packed {src, dinv[src]} records
// ---------------------------------------------------------------------------
__global__ void scatter_kernel(const int* __restrict__ src, const int* __restrict__ dst,
                               const int* __restrict__ row_ptr, int* __restrict__ wp,
                               const float* __restrict__ dinv,
                               int2* __restrict__ edges, int E) {
    int e = blockIdx.x * blockDim.x + threadIdx.x;
    if (e < E) {
        int d = dst[e];
        int s = src[e];
        int p = atomicAdd(&wp[d], 1);
        int2 pk;
        pk.x = s;
        pk.y = __float_as_int(dinv[s]);
        edges[row_ptr[d] + p] = pk;
    }
}

// ---------------------------------------------------------------------------
// merged prep: h0 (bf16) + transposed bf16 weights + zero counts/wp.
// ---------------------------------------------------------------------------
__global__ void prep_kernel(const int* __restrict__ x, const float* __restrict__ emb,
                            const float* __restrict__ W1, const float* __restrict__ W2,
                            const float* __restrict__ Wl,
                            unsigned short* __restrict__ h0,
                            unsigned short* __restrict__ W1t,
                            unsigned short* __restrict__ W2t,
                            unsigned short* __restrict__ Wlt,
                            int* __restrict__ counts, int* __restrict__ wp,
                            int nu, int n) {
    int i = blockIdx.x * blockDim.x + threadIdx.x;
    int H = n * 16;
    if (i < H) {
        int node = i >> 4, c8 = i & 15;
        int row = (node < nu) ? 0 : (x[node] - nu + 1);
        float4 f0 = reinterpret_cast<const float4*>(emb)[(size_t)row * 32 + c8 * 2];
        float4 f1 = reinterpret_cast<const float4*>(emb)[(size_t)row * 32 + c8 * 2 + 1];
        union { unsigned short s[8]; uint4 v; } o;
        o.s[0] = f2bf(f0.x); o.s[1] = f2bf(f0.y); o.s[2] = f2bf(f0.z); o.s[3] = f2bf(f0.w);
        o.s[4] = f2bf(f1.x); o.s[5] = f2bf(f1.y); o.s[6] = f2bf(f1.z); o.s[7] = f2bf(f1.w);
        *reinterpret_cast<uint4*>(h0 + (size_t)node * 128 + c8 * 8) = o.v;
        return;
    }
    int j = i - H;
    if (j < 32768) {
        int nn = j >> 7, kk = j & 127;
        W1t[j] = f2bf(W1[kk * 256 + nn]);
        return;
    }
    if (j < 65536) {
        int jj = j - 32768;
        int nn = jj >> 8, kk = jj & 255;
        W2t[jj] = f2bf(W2[kk * 128 + nn]);
        return;
    }
    if (j < 73728) {
        int jj = j - 65536;
        int nn = jj >> 7, kk = jj & 127;
        Wlt[jj] = f2bf(Wl[kk * 64 + nn]);
        return;
    }
    int z = j - 73728;
    if (z < n) { counts[z] = 0; return; }
    z -= n;
    if (z < n) { wp[z] = 0; }
}

// ---------------------------------------------------------------------------
// one-wave aggregation of node v -> LDS row (bf16).
// out_row[d] = bf16( dinv[v]*(sum_e dinv[s]*in[s][d] + dinv[v]*in[v][d]) + bias[d] )
// ---------------------------------------------------------------------------
static __device__ __forceinline__ void agg_node_to_lds(
    const unsigned short* __restrict__ in, unsigned short* lds_row,
    int v, int lane, const int* __restrict__ row_ptr, const int* __restrict__ cnt,
    const int2* __restrict__ edges, const float* __restrict__ dinv,
    const float* __restrict__ bias, int relu) {
    int l16 = lane & 15;
    int g = lane >> 4;
    float acc[8] = {0.f, 0.f, 0.f, 0.f, 0.f, 0.f, 0.f, 0.f};
    int s0 = row_ptr[v];
    int s1 = s0 + cnt[v];
    int e = s0 + g;
    for (; e + 4 < s1; e += 8) {
        int2 pa = edges[e];
        int2 pb = edges[e + 4];
        float wa = __int_as_float(pa.y);
        float wb = __int_as_float(pb.y);
        uint4 ra = *reinterpret_cast<const uint4*>(in + (size_t)pa.x * 128 + l16 * 8);
        uint4 rb = *reinterpret_cast<const uint4*>(in + (size_t)pb.x * 128 + l16 * 8);
        acc[0] = fmaf(wa, bflo(ra.x), acc[0]);
        acc[1] = fmaf(wa, bfhi(ra.x), acc[1]);
        acc[2] = fmaf(wa, bflo(ra.y), acc[2]);
        acc[3] = fmaf(wa, bfhi(ra.y), acc[3]);
        acc[4] = fmaf(wa, bflo(ra.z), acc[4]);
        acc[5] = fmaf(wa, bfhi(ra.z), acc[5]);
        acc[6] = fmaf(wa, bflo(ra.w), acc[6]);
        acc[7] = fmaf(wa, bfhi(ra.w), acc[7]);
        acc[0] = fmaf(wb, bflo(rb.x), acc[0]);
        acc[1] = fmaf(wb, bfhi(rb.x), acc[1]);
        acc[2] = fmaf(wb, bflo(rb.y), acc[2]);
        acc[3] = fmaf(wb, bfhi(rb.y), acc[3]);
        acc[4] = fmaf(wb, bflo(rb.z), acc[4]);
        acc[5] = fmaf(wb, bfhi(rb.z), acc[5]);
        acc[6] = fmaf(wb, bflo(rb.w), acc[6]);
        acc[7] = fmaf(wb, bfhi(rb.w), acc[7]);
    }
    if (e < s1) {
        int2 pa = edges[e];
        float wa = __int_as_float(pa.y);
        uint4 ra = *reinterpret_cast<const uint4*>(in + (size_t)pa.x * 128 + l16 * 8);
        acc[0] = fmaf(wa, bflo(ra.x), acc[0]);
        acc[1] = fmaf(wa, bfhi(ra.x), acc[1]);
        acc[2] = fmaf(wa, bflo(ra.y), acc[2]);
        acc[3] = fmaf(wa, bfhi(ra.y), acc[3]);
        acc[4] = fmaf(wa, bflo(ra.z), acc[4]);
        acc[5] = fmaf(wa, bfhi(ra.z), acc[5]);
        acc[6] = fmaf(wa, bflo(ra.w), acc[6]);
        acc[7] = fmaf(wa, bfhi(ra.w), acc[7]);
    }
#pragma unroll
    for (int d = 0; d < 8; ++d) {
        acc[d] += __shfl_xor(acc[d], 16, 64);
        acc[d] += __shfl_xor(acc[d], 32, 64);
    }
    if (g == 0) {
        float dv = dinv[v];
        uint4 sp = *reinterpret_cast<const uint4*>(in + (size_t)v * 128 + l16 * 8);
        float self[8] = {bflo(sp.x), bfhi(sp.x), bflo(sp.y), bfhi(sp.y),
                         bflo(sp.z), bfhi(sp.z), bflo(sp.w), bfhi(sp.w)};
        union { unsigned short s[8]; uint4 u; } o;
#pragma unroll
        for (int d = 0; d < 8; ++d) {
            float val = (acc[d] + dv * self[d]) * dv;
            if (bias) val += bias[l16 * 8 + d];
            if (relu) val = fmaxf(val, 0.f);
            o.s[d] = f2bf(val);
        }
        *reinterpret_cast<uint4*>(lds_row + l16 * 8) = o.u;
    }
}

// ---------------------------------------------------------------------------
// fused conv1: block = 16 nodes.
//   agg(h0) -> zt (LDS) ; h1 = relu(zt@W1t^T + b1) -> h1t (LDS) ;
//   hw2 = h1t@W2t^T -> global.
// ---------------------------------------------------------------------------
__global__ __launch_bounds__(256) void fused_conv1_kernel(
    const unsigned short* __restrict__ h0b, unsigned short* __restrict__ hw2b,
    const int* __restrict__ row_ptr, const int* __restrict__ cnt,
    const int2* __restrict__ edges, const float* __restrict__ dinv,
    const unsigned short* __restrict__ W1t, const float* __restrict__ b1,
    const unsigned short* __restrict__ W2t) {
    __shared__ unsigned short zt[16][136];    // 128 + 8 pad
    __shared__ unsigned short h1t[16][264];   // 256 + 8 pad
    int wid = threadIdx.x >> 6, lane = threadIdx.x & 63;
    int base = blockIdx.x * 16;
    // agg phase: wave wid handles 4 nodes
#pragma unroll
    for (int q = 0; q < 4; ++q) {
        int loc = wid * 4 + q;
        agg_node_to_lds(h0b, &zt[loc][0], base + loc, lane, row_ptr, cnt, edges, dinv,
                        nullptr, 0);
    }
    __syncthreads();
    int lr = lane & 15, kg = (lane >> 4) * 8;
    int rq = (lane >> 4) * 4;
    // gemm1: h1[16][256], wave wid computes cols [wid*64, +64), K=128
    {
        int bn = wid * 64;
        f32x4 acc[4] = {{0,0,0,0},{0,0,0,0},{0,0,0,0},{0,0,0,0}};
        for (int k0 = 0; k0 < 128; k0 += 32) {
            bf16x8 a = *reinterpret_cast<const bf16x8*>(&zt[lr][k0 + kg]);
#pragma unroll
            for (int c = 0; c < 4; ++c) {
                bf16x8 b = *reinterpret_cast<const bf16x8*>(W1t + (size_t)(bn + c * 16 + lr) * 128 + k0 + kg);
                acc[c] = __builtin_amdgcn_mfma_f32_16x16x32_bf16(a, b, acc[c], 0, 0, 0);
            }
        }
#pragma unroll
        for (int c = 0; c < 4; ++c) {
            int col = bn + c * 16 + lr;
            float bs = b1[col];
#pragma unroll
            for (int q = 0; q < 4; ++q) {
                float vv = fmaxf(acc[c][q] + bs, 0.f);
                h1t[rq + q][col] = f2bf(vv);
            }
        }
    }
    __syncthreads();
    // gemm2: hw2[16][128], wave wid computes cols [wid*32, +32), K=256
    {
        int bn = wid * 32;
        f32x4 acc[2] = {{0,0,0,0},{0,0,0,0}};
        for (int k0 = 0; k0 < 256; k0 += 32) {
            bf16x8 a = *reinterpret_cast<const bf16x8*>(&h1t[lr][k0 + kg]);
#pragma unroll
            for (int c = 0; c < 2; ++c) {
                bf16x8 b = *reinterpret_cast<const bf16x8*>(W2t + (size_t)(bn + c * 16 + lr) * 256 + k0 + kg);
                acc[c] = __builtin_amdgcn_mfma_f32_16x16x32_bf16(a, b, acc[c], 0, 0, 0);
            }
        }
#pragma unroll
        for (int c = 0; c < 2; ++c) {
            int col = bn + c * 16 + lr;
#pragma unroll
            for (int q = 0; q < 4; ++q)
                hw2b[(size_t)(base + rq + q) * 128 + col] = f2bf(acc[c][q]);
        }
    }
}

// ---------------------------------------------------------------------------
// fused conv2: block = 16 nodes.
//   h2 = relu(agg(hw2) + b2) -> LDS ; h3 = relu(h2@Wlt^T + bl) -> global.
// ---------------------------------------------------------------------------
__global__ __launch_bounds__(256) void fused_conv2_kernel(
    const unsigned short* __restrict__ hw2b, unsigned short* __restrict__ h3b,
    const int* __restrict__ row_ptr, const int* __restrict__ cnt,
    const int2* __restrict__ edges, const float* __restrict__ dinv,
    const float* __restrict__ b2,
    const unsigned short* __restrict__ Wlt, const float* __restrict__ bl) {
    __shared__ unsigned short ht[16][136];
    int wid = threadIdx.x >> 6, lane = threadIdx.x & 63;
    int base = blockIdx.x * 16;
#pragma unroll
    for (int q = 0; q < 4; ++q) {
        int loc = wid * 4 + q;
        agg_node_to_lds(hw2b, &ht[loc][0], base + loc, lane, row_ptr, cnt, edges, dinv,
                        b2, 1);
    }
    __syncthreads();
    int lr = lane & 15, kg = (lane >> 4) * 8;
    int rq = (lane >> 4) * 4;
    // gemm3: h3[16][64], wave wid computes cols [wid*16, +16), K=128
    f32x4 acc = {0, 0, 0, 0};
    for (int k0 = 0; k0 < 128; k0 += 32) {
        bf16x8 a = *reinterpret_cast<const bf16x8*>(&ht[lr][k0 + kg]);
        bf16x8 b = *reinterpret_cast<const bf16x8*>(Wlt + (size_t)(wid * 16 + lr) * 128 + k0 + kg);
        acc = __builtin_amdgcn_mfma_f32_16x16x32_bf16(a, b, acc, 0, 0, 0);
    }
    int col = wid * 16 + lr;
    float bs = bl[col];
#pragma unroll
    for (int q = 0; q < 4; ++q) {
        float vv = fmaxf(acc[q] + bs, 0.f);
        h3b[(size_t)(base + rq + q) * 64 + col] = f2bf(vv);
    }
}

// ---------------------------------------------------------------------------
// final: out[i][j] = clip(dot64(users[i], items[j]), 1, 5)  via bf16 MFMA.
// Block = 4 waves; each wave a 64x64 tile -> block tile 128x128.
// Epilogue: per-wave LDS transpose chunk -> float4 stores (256B segments).
// ---------------------------------------------------------------------------
__global__ __launch_bounds__(256) void final_gemm_kernel(
    const short* __restrict__ h3b, float* __restrict__ out, int nu, int ni) {
    __shared__ float tile[4][16][65];
    int wid = threadIdx.x >> 6, lane = threadIdx.x & 63;
    int row0 = blockIdx.x * 128 + (wid >> 1) * 64;
    int col0 = blockIdx.y * 128 + (wid & 1) * 64;
    int lr = lane & 15;
    int kg = (lane >> 4) * 8;
    const short* Au = h3b;
    const short* Bi = h3b + (size_t)nu * 64;
    bf16x8 a[4][2], b[4][2];
#pragma unroll
    for (int r = 0; r < 4; ++r)
#pragma unroll
        for (int kt = 0; kt < 2; ++kt) {
            a[r][kt] = *reinterpret_cast<const bf16x8*>(Au + (size_t)(row0 + r * 16 + lr) * 64 + kt * 32 + kg);
            b[r][kt] = *reinterpret_cast<const bf16x8*>(Bi + (size_t)(col0 + r * 16 + lr) * 64 + kt * 32 + kg);
        }
    f32x4 acc[4][4];
#pragma unroll
    for (int r = 0; r < 4; ++r)
#pragma unroll
        for (int c = 0; c < 4; ++c) {
            f32x4 z = {0.f, 0.f, 0.f, 0.f};
            z = __builtin_amdgcn_mfma_f32_16x16x32_bf16(a[r][0], b[c][0], z, 0, 0, 0);
            z = __builtin_amdgcn_mfma_f32_16x16x32_bf16(a[r][1], b[c][1], z, 0, 0, 0);
            acc[r][c] = z;
        }
    int rq = (lane >> 4) * 4;
    int orow = lane >> 4;
#pragma unroll
    for (int r = 0; r < 4; ++r) {
        __syncthreads();
#pragma unroll
        for (int c = 0; c < 4; ++c)
#pragma unroll
            for (int q = 0; q < 4; ++q) {
                float v = acc[r][c][q];
                v = fminf(fmaxf(v, 1.f), 5.f);
                tile[wid][rq + q][c * 16 + lr] = v;
            }
        __syncthreads();
#pragma unroll
        for (int rr = 0; rr < 4; ++rr) {
            float4 vv = *reinterpret_cast<const float4*>(&tile[wid][rr * 4 + orow][lr * 4]);
            *reinterpret_cast<float4*>(
                &out[(size_t)(row0 + r * 16 + rr * 4 + orow) * ni + col0 + lr * 4]) = vv;
        }
    }
}

// ---------------------------------------------------------------------------
extern "C" void kernel_launch(void* const* d_in, const int* in_sizes, int n_in,
                              void* d_out, int out_size, void* d_ws, size_t ws_size,
                              hipStream_t stream) {
    const int*   x   = (const int*)d_in[0];
    const int*   ei  = (const int*)d_in[1];
    const float* emb = (const float*)d_in[3];
    const float* W1  = (const float*)d_in[4];
    const float* b1  = (const float*)d_in[5];
    const float* W2  = (const float*)d_in[6];
    const float* b2  = (const float*)d_in[7];
    const float* Wl  = (const float*)d_in[8];
    const float* bl  = (const float*)d_in[9];
    float* out = (float*)d_out;

    const int n   = in_sizes[0];                 // 16384
    const int E   = in_sizes[1] / 2;             // 524288
    const int h1d = in_sizes[5];                 // 256
    const int d   = in_sizes[4] / h1d;           // 128
    const int embrows = in_sizes[3] / d;         // 8193
    const int nu  = n - (embrows - 1);           // 8192
    const int ni  = n - nu;                      // 8192

    const int* srcp = ei;
    const int* dstp = ei + E;

    char* w = (char*)d_ws;
    int*   counts  = (int*)(w + 0);
    int*   row_ptr = (int*)(w + (64 << 10));
    int*   wp      = (int*)(w + (128 << 10));
    float* dinv    = (float*)(w + (192 << 10));
    unsigned short* W1t = (unsigned short*)(w + (256 << 10));
    unsigned short* W2t = (unsigned short*)(w + (320 << 10));
    unsigned short* Wlt = (unsigned short*)(w + (384 << 10));
    int2*  edges   = (int2*)(w + (1 << 20));
    unsigned short* h0b  = (unsigned short*)(w + (8  << 20));
    unsigned short* hw2b = (unsigned short*)(w + (12 << 20));
    unsigned short* h3b  = (unsigned short*)(w + (16 << 20));

    // prep: h0 bf16 + transposed bf16 weights + zero counters
    {
        int total = n * 16 + 73728 + 2 * n;
        prep_kernel<<<(total + 255) / 256, 256, 0, stream>>>(
            x, emb, W1, W2, Wl, h0b, W1t, W2t, Wlt, counts, wp, nu, n);
    }

    // graph structure
    count_kernel<<<(E + 255) / 256, 256, 0, stream>>>(dstp, counts, E);
    scan_kernel<<<1, 256, 0, stream>>>(counts, row_ptr, dinv, n);
    scatter_kernel<<<(E + 255) / 256, 256, 0, stream>>>(srcp, dstp, row_ptr, wp, dinv, edges, E);

    // conv1 fused: agg1 -> gemm1 -> gemm2  => hw2
    fused_conv1_kernel<<<n / 16, 256, 0, stream>>>(
        h0b, hw2b, row_ptr, counts, edges, dinv, W1t, b1, W2t);

    // conv2 fused: agg2 -> gemm3  => h3
    fused_conv2_kernel<<<n / 16, 256, 0, stream>>>(
        hw2b, h3b, row_ptr, counts, edges, dinv, b2, Wlt, bl);

    // result = clip(users @ items.T, 1, 5)
    {
        dim3 g(nu / 128, ni / 128);
        final_gemm_kernel<<<g, 256, 0, stream>>>((const short*)h3b, out, nu, ni);
    }
}